// Round 4
// baseline (1188.508 us; speedup 1.0000x reference)
//
#include <hip/hip_runtime.h>
#include <cstdint>
#include <cstddef>

// ---------------------------------------------------------------------------
// WindowAttention: B=1024 windows, N=216 tokens, H=6 heads, D=32, C=192.
// K0 prep (weights->bf16, bias expand, x->bf16 into out-region upper halves) ->
// K1 fused qkv+attention (software-pipelined: phase1(h+1) || phase2(h)) ->
// K2 proj GEMM in-place on d_out.
//
// Round 3 (retry; previous attempt died on container infra, not the kernel).
// Pipeline the head loop. One barrier per head (7 vs 12); while a wave's
// phase-2 chain (S-MFMA -> exp -> pack -> PV-MFMA) stalls, its own
// phase-1(h+1) stream (36 independent MFMAs + global loads) fills the MFMA
// pipe. Only ks/vT are double-buffered; q is same-wave produce/consume so a
// single qs buffer suffices (in-wave LDS ordering). ks shrunk to 216 rows:
// pad k-rows are CLAMPED reads (bias -inf already zeroes p for m>=216, it
// only needs finite S). LDS = 81,536 B <= 81,920 -> 2 blocks/CU at
// 1024 threads / __launch_bounds__(1024,8) (the r1-proven residency combo).
// attnb layout -> [h][216][32] bf16: dense 1KB/wave/head writes (fixes the
// 1.83x partial-line write amplification seen in WRITE_SIZE).
//
// k-order permutation trick: MFMA dot products are invariant under a shared
// permutation of the K dimension. q/k d-columns interleaved (col'=2*(d&15)
// +(d>>4)); vT m-columns permuted as pos = 8*((m>>2)&3)+4*((m>>4)&1)+(m&3)
// within each 32-block so the packed P fragment lines up with PV's A-operand.
// ---------------------------------------------------------------------------

typedef __attribute__((ext_vector_type(8))) short short8;   // 8 x bf16 frag
typedef __attribute__((ext_vector_type(4))) float f32x4;    // MFMA C/D
typedef unsigned short u16;
typedef unsigned int   u32;

#define SCALE_F 0.17677669529663687f  /* 32^-0.5 */

// LDS layout (attn): all byte offsets 16B-aligned
#define QS_OFF   0        // [216][40] u16 = 17280 (single: same-wave use)
#define KS0_OFF  17280    // [216][40] u16 = 17280
#define KS1_OFF  34560    // [216][40] u16 = 17280
#define VT0_OFF  51840    // [32][232] u16 = 14848 (perm cols; m-pads zeroed)
#define VT1_OFF  66688    // [32][232] u16 = 14848
#define ATTN_LDS 81536    // <= 81920 -> 2 blocks/CU

#define PROJ_LDS 76800    // [192][200] u16 weights only -> 2 blocks/CU

__device__ __forceinline__ u16 f2bf(float f) {
  union { float f; u32 u; } v; v.f = f;
  return (u16)((v.u + 0x7fffu + ((v.u >> 16) & 1u)) >> 16);  // RNE
}

__device__ __forceinline__ f32x4 mfma16(short8 a, short8 b, f32x4 c) {
  return __builtin_amdgcn_mfma_f32_16x16x32_bf16(a, b, c, 0, 0, 0);
}

// ---------------------------------------------------------------------------
// K0: x->bf16 (upper half of each block's out region), qkv_w->bf16,
// proj_w->bf16, bias expand to [h][c][n:224][l:16][t:2] bf16.
// m = c*32 + t*16 + l. m>=216 -> -inf bf16 (0xFF80) so exp()->0. n>=216 -> 0.
// ---------------------------------------------------------------------------
__global__ void prep_kernel(const float* __restrict__ x,
                            const float* __restrict__ qkv_w,
                            const float* __restrict__ proj_w,
                            const float* __restrict__ bias_table,
                            u16* __restrict__ wb,
                            u16* __restrict__ pwb,
                            u16* __restrict__ biasp,
                            float* outbuf) {
  const int tid = blockIdx.x * blockDim.x + threadIdx.x;
  const int stride = gridDim.x * blockDim.x;
  // x -> bf16 scratch: block b's slice goes to bytes [82944, 165888) of its
  // own out region (lower part holds the [h][216][32] bf16 attn scratch).
  const float4* x4 = (const float4*)x;
  for (int i = tid; i < 1024 * 10368; i += stride) {
    const int b = i / 10368, r = i % 10368;
    const float4 v = x4[i];
    union { u16 s[4]; unsigned long long u; } pk;
    pk.s[0] = f2bf(v.x); pk.s[1] = f2bf(v.y);
    pk.s[2] = f2bf(v.z); pk.s[3] = f2bf(v.w);
    *(unsigned long long*)((u16*)(outbuf + (size_t)b * 41472) + 41472 + r * 4) = pk.u;
  }
  for (int i = tid; i < 576 * 192; i += stride) wb[i] = f2bf(qkv_w[i]);
  for (int i = tid; i < 192 * 192; i += stride) pwb[i] = f2bf(proj_w[i]);
  // bias layout: [h][c][n:224][l:16][t:2]; lane uint4 covers l=quad*4..+3.
  for (int i = tid; i < 6 * 7 * 224 * 16 * 2; i += stride) {
    const int t = i & 1;
    int j = i >> 1;
    const int l = j & 15;  j >>= 4;
    const int n = j % 224; j /= 224;
    const int c = j % 7;
    const int h = j / 7;
    const int m = c * 32 + t * 16 + l;
    u16 val;
    if (n >= 216)      val = 0;        // pad q-rows: finite, discarded
    else if (m >= 216) val = 0xFF80;   // -inf bf16 -> exp = 0
    else {
      const int di = n / 36 - m / 36;
      const int dj = (n / 6) % 6 - (m / 6) % 6;
      const int dk = n % 6 - m % 6;
      const int idx = (di + 5) * 17 + (dj + 5) * 11 + (dk + 5);
      val = f2bf(bias_table[idx * 6 + h]);
    }
    biasp[i] = val;
  }
}

// ---------------------------------------------------------------------------
// Fused step: phase2(h) from ksc/vtc/qs, interleaved with phase1(h+1) into
// ksn/vtn/qs (DOP1). qs hazard is same-wave only: qa read precedes qs writes
// in program order; compiler enforces LDS ordering via lgkmcnt.
// ---------------------------------------------------------------------------
template <bool DOP1>
__device__ __forceinline__ void head_step(
    int h, const u16* __restrict__ xb, const u16* __restrict__ wb,
    const u16* __restrict__ biasp, u16* __restrict__ attnb,
    u16* qs, const u16* ksc, const u16* vtc, u16* ksn, u16* vtn,
    int wave, int quad, int lcol) {
  const int s = wave;
  const int qr0 = s * 16 + lcol;
  const int qr  = qr0 < 216 ? qr0 : 215;      // clamp: garbage lanes discarded
  const short8 qa = *(const short8*)(qs + qr * 40 + quad * 8);

  f32x4 acc[6] = {};                          // phase1(h+1) accumulators
  const int ar = qr;                          // same clamped row for x

  f32x4 o0 = {}, o1 = {};
  float rsum = 0.0f;

#pragma unroll
  for (int c = 0; c < 7; ++c) {
    // ---- phase2 step c ----
    const short8 kb0 = *(const short8*)(ksc + (c * 32 + lcol) * 40 + quad * 8);
    const int kr1 = c * 32 + 16 + lcol;
    const short8 kb1 = *(const short8*)(ksc + (kr1 < 216 ? kr1 : 215) * 40 + quad * 8);
    const f32x4 z = {};
    const f32x4 s0 = mfma16(kb0, qa, z);      // S^T rows m=c*32+quad*4+r
    const f32x4 s1 = mfma16(kb1, qa, z);      // S^T rows m=c*32+16+quad*4+r
    const uint4 bq = *(const uint4*)(biasp
        + ((size_t)((h * 7 + c) * 224 + s * 16 + lcol)) * 32 + quad * 8);
    const u32* bw = (const u32*)&bq;
    float p0[4], p1[4];
#pragma unroll
    for (int r = 0; r < 4; ++r) {
      union { u32 u; float f; } b0, b1;
      b0.u = bw[r] << 16;            // t=0 bias (low short)
      b1.u = bw[r] & 0xFFFF0000u;    // t=1 bias (high short)
      p0[r] = __expf(__builtin_fmaf(s0[r], SCALE_F, b0.f));
      p1[r] = __expf(__builtin_fmaf(s1[r], SCALE_F, b1.f));
      rsum += p0[r] + p1[r];
    }
    union { u32 w[4]; short8 v; } pk;
    pk.w[0] = (u32)f2bf(p0[0]) | ((u32)f2bf(p0[1]) << 16);
    pk.w[1] = (u32)f2bf(p0[2]) | ((u32)f2bf(p0[3]) << 16);
    pk.w[2] = (u32)f2bf(p1[0]) | ((u32)f2bf(p1[1]) << 16);
    pk.w[3] = (u32)f2bf(p1[2]) | ((u32)f2bf(p1[3]) << 16);
    const short8 vb0 = *(const short8*)(vtc + lcol * 232 + c * 32 + quad * 8);
    const short8 vb1 = *(const short8*)(vtc + (16 + lcol) * 232 + c * 32 + quad * 8);
    o0 = mfma16(pk.v, vb0, o0);
    o1 = mfma16(pk.v, vb1, o1);

    // ---- phase1(h+1) step kk=c: independent MFMA stream fills the stalls ----
    if (DOP1 && c < 6) {
      const short8 a = *(const short8*)(xb + ar * 192 + c * 32 + quad * 8);
#pragma unroll
      for (int j = 0; j < 6; ++j) {    // 0,1=q(lo,hi) 2,3=k 4,5=v
        const int fbase = (j >> 1) * 192 + (h + 1) * 32 + (j & 1) * 16;
        const short8 bf = *(const short8*)(wb + (fbase + lcol) * 192 + c * 32 + quad * 8);
        acc[j] = mfma16(a, bf, acc[j]);
      }
    }
  }

  // ---- phase2 epilogue: denom + dense [h][216][32] store ----
  rsum += __shfl_xor(rsum, 16);
  rsum += __shfl_xor(rsum, 32);
  const float inv = 1.0f / rsum;
#pragma unroll
  for (int r = 0; r < 4; ++r) {
    const float invr = __shfl(inv, quad * 4 + r, 16);
    const int n = s * 16 + quad * 4 + r;
    if (n < 216) {
      attnb[(h * 216 + n) * 32 + lcol]      = f2bf(o0[r] * invr);
      attnb[(h * 216 + n) * 32 + 16 + lcol] = f2bf(o1[r] * invr);
    }
  }

  // ---- phase1(h+1) stores ----
  if (DOP1) {
    const int nb = s * 16 + quad * 4;
#pragma unroll
    for (int r = 0; r < 4; ++r) {
      const int n = nb + r;
      if (n < 216) {
        *(u32*)(qs + n * 40 + 2 * lcol) =
            (u32)f2bf(acc[0][r]) | ((u32)f2bf(acc[1][r]) << 16);
        *(u32*)(ksn + n * 40 + 2 * lcol) =
            (u32)f2bf(acc[2][r]) | ((u32)f2bf(acc[3][r]) << 16);
        const int pm = (n & ~31) | (((n >> 2) & 3) << 3) | (((n >> 4) & 1) << 2) | (n & 3);
        vtn[lcol * 232 + pm]        = f2bf(acc[4][r]);
        vtn[(16 + lcol) * 232 + pm] = f2bf(acc[5][r]);
      }
    }
  }
}

// ---------------------------------------------------------------------------
// K1: per-window fused qkv + attention, pipelined. 1024 thr, 2 blocks/CU.
// ---------------------------------------------------------------------------
__global__ __launch_bounds__(1024, 8)
void attn_kernel(const u16* __restrict__ wb, const u16* __restrict__ biasp,
                 float* outbuf) {
  extern __shared__ char smem[];
  u16* qs  = (u16*)(smem + QS_OFF);
  u16* ks0 = (u16*)(smem + KS0_OFF);
  u16* ks1 = (u16*)(smem + KS1_OFF);
  u16* vt0 = (u16*)(smem + VT0_OFF);
  u16* vt1 = (u16*)(smem + VT1_OFF);

  const int b = blockIdx.x;
  const int tid = threadIdx.x;
  const int wave = tid >> 6;       // 0..13 active; 14,15 barrier-only
  const int lane = tid & 63;
  const int quad = lane >> 4;
  const int lcol = lane & 15;
  const bool active = wave < 14;

  const u16* xb    = (const u16*)(outbuf + (size_t)b * 41472) + 41472;  // [216][192]
  u16*       attnb = (u16*)(outbuf + (size_t)b * 41472);                // [6][216][32]

  // zero vT pad cols (perm positions 192+{20..23,28..31}) in BOTH buffers
  for (int i = tid; i < 512; i += 1024) {
    const int bufi = i >> 8;
    const int d  = (i >> 3) & 31;
    const int jj = i & 7;
    u16* vt = bufi ? vt1 : vt0;
    vt[d * 232 + 192 + 20 + (jj & 3) + ((jj >> 2) << 3)] = 0;
  }

  // ---- prologue: phase1(h=0) into qs/ks0/vt0 ----
  if (active) {
    f32x4 acc[6] = {};
    const int ar0 = wave * 16 + lcol;
    const int ar  = ar0 < 216 ? ar0 : 215;
#pragma unroll
    for (int kk = 0; kk < 6; ++kk) {
      const short8 a = *(const short8*)(xb + ar * 192 + kk * 32 + quad * 8);
#pragma unroll
      for (int j = 0; j < 6; ++j) {
        const int fbase = (j >> 1) * 192 + (j & 1) * 16;   // h=0
        const short8 bf = *(const short8*)(wb + (fbase + lcol) * 192 + kk * 32 + quad * 8);
        acc[j] = mfma16(a, bf, acc[j]);
      }
    }
    const int nb = wave * 16 + quad * 4;
#pragma unroll
    for (int r = 0; r < 4; ++r) {
      const int n = nb + r;
      if (n < 216) {
        *(u32*)(qs + n * 40 + 2 * lcol) =
            (u32)f2bf(acc[0][r]) | ((u32)f2bf(acc[1][r]) << 16);
        *(u32*)(ks0 + n * 40 + 2 * lcol) =
            (u32)f2bf(acc[2][r]) | ((u32)f2bf(acc[3][r]) << 16);
        const int pm = (n & ~31) | (((n >> 2) & 3) << 3) | (((n >> 4) & 1) << 2) | (n & 3);
        vt0[lcol * 232 + pm]        = f2bf(acc[4][r]);
        vt0[(16 + lcol) * 232 + pm] = f2bf(acc[5][r]);
      }
    }
  }
  __syncthreads();

  // ---- pipelined heads 0..4: phase2(h) || phase1(h+1) ----
  for (int h = 0; h < 5; ++h) {
    const bool even = (h & 1) == 0;
    const u16* ksc = even ? ks0 : ks1;
    const u16* vtc = even ? vt0 : vt1;
    u16* ksn = even ? ks1 : ks0;
    u16* vtn = even ? vt1 : vt0;
    if (active)
      head_step<true>(h, xb, wb, biasp, attnb, qs, ksc, vtc, ksn, vtn,
                      wave, quad, lcol);
    __syncthreads();
  }
  // ---- tail: phase2(5) only (buffers: h=5 -> odd -> ks1/vt1) ----
  if (active)
    head_step<false>(5, xb, wb, biasp, attnb, qs, ks1, vt1, ks0, vt0,
                     wave, quad, lcol);
}

// ---------------------------------------------------------------------------
// K2: out = attn @ proj_w^T + proj_b, block-local in-place on d_out.
// proj_w staged in LDS (padded stride 200); A-fragments loaded from GLOBAL
// attnb ([kk][216][32] bf16, dense) before the barrier; in-place fp32 writes
// after (the pre-barrier vmcnt drain orders all reads before any write).
// ---------------------------------------------------------------------------
__global__ __launch_bounds__(1024, 8)
void proj_kernel(const u16* __restrict__ pwb, const float* __restrict__ proj_b,
                 float* outbuf) {
  extern __shared__ char smem[];
  u16* pws = (u16*)smem;   // [192][200]
  const int b = blockIdx.x, tid = threadIdx.x;
  const int wave = tid >> 6, lane = tid & 63, quad = lane >> 4, lcol = lane & 15;
  float* myout = outbuf + (size_t)b * 41472;
  const u16* attnb = (const u16*)myout;   // [6][216][32]

  for (int i = tid; i < 192 * 24; i += 1024) {
    const int row = i / 24, c8 = i % 24;
    *(short8*)(pws + row * 200 + c8 * 8) = *(const short8*)(pwb + row * 192 + c8 * 8);
  }

  short8 a[6] = {};
  const bool active = wave < 14;
  if (active) {
    const int arow = wave * 16 + lcol;
    if (arow < 216) {
#pragma unroll
      for (int kk = 0; kk < 6; ++kk)
        a[kk] = *(const short8*)(attnb + (kk * 216 + arow) * 32 + quad * 8);
    }
  }
  __syncthreads();

  if (active) {
    for (int nt = 0; nt < 12; ++nt) {
      f32x4 acc = {};
#pragma unroll
      for (int kk = 0; kk < 6; ++kk) {
        const short8 bf = *(const short8*)(pws + (nt * 16 + lcol) * 200 + kk * 32 + quad * 8);
        acc = mfma16(a[kk], bf, acc);
      }
      const float pbv = proj_b[nt * 16 + lcol];
      const int nb = wave * 16 + quad * 4;
#pragma unroll
      for (int r = 0; r < 4; ++r) {
        const int n = nb + r;
        if (n < 216) myout[n * 192 + nt * 16 + lcol] = acc[r] + pbv;
      }
    }
  }
}

// ---------------------------------------------------------------------------
extern "C" void kernel_launch(void* const* d_in, const int* in_sizes, int n_in,
                              void* d_out, int out_size, void* d_ws, size_t ws_size,
                              hipStream_t stream) {
  (void)in_sizes; (void)n_in; (void)out_size; (void)ws_size;
  const float* x          = (const float*)d_in[0];
  const float* qkv_w      = (const float*)d_in[1];
  const float* proj_w     = (const float*)d_in[2];
  const float* proj_b     = (const float*)d_in[3];
  const float* bias_table = (const float*)d_in[4];
  float* out = (float*)d_out;

  u16* wb    = (u16*)d_ws;                              // 221184 B
  u16* pwb   = (u16*)((char*)d_ws + 221184);            //  73728 B
  u16* biasp = (u16*)((char*)d_ws + 294912);            // 602112 B

  (void)hipFuncSetAttribute((const void*)attn_kernel,
                            hipFuncAttributeMaxDynamicSharedMemorySize, ATTN_LDS);
  (void)hipFuncSetAttribute((const void*)proj_kernel,
                            hipFuncAttributeMaxDynamicSharedMemorySize, PROJ_LDS);

  prep_kernel<<<dim3(1024), dim3(256), 0, stream>>>(x, qkv_w, proj_w, bias_table,
                                                    wb, pwb, biasp, out);
  attn_kernel<<<dim3(1024), dim3(1024), ATTN_LDS, stream>>>(wb, biasp, out);
  proj_kernel<<<dim3(1024), dim3(1024), PROJ_LDS, stream>>>(pwb, proj_b, out);
}

// Round 5
// 788.673 us; speedup vs baseline: 1.5070x; 1.5070x over previous
//
#include <hip/hip_runtime.h>
#include <cstdint>
#include <cstddef>

// ---------------------------------------------------------------------------
// WindowAttention: B=1024 windows, N=216 tokens, H=6 heads, D=32, C=192.
// K0 prep (weights->bf16, bias expand, x->bf16 into out-region upper halves) ->
// K1 fused qkv+attention (software-pipelined: phase1(h+1) || phase2(h)) ->
// K2 proj GEMM in-place on d_out.
//
// Round 5: SAME pipelined structure as round 4, ONE change: attn
// __launch_bounds__(1024,8) -> (1024,4). Round 4's 64-VGPR cap forced a
// catastrophic spill (VGPR_Count=32, hbm_bytes 3.4GB of scratch, MfmaUtil
// 4.1%). The pipelined head_step needs ~37 persistent + ~40 transient regs;
// cap 128 lets it codegen properly. 1 block/CU (16 waves, 4/SIMD): the
// pipeline supplies intra-wave ILP (phase1(h+1)'s 36 independent MFMAs fill
// phase2(h)'s S->exp->pack->PV serial-chain stalls), so fewer-but-unstrangled
// waves should win. Clean A/B vs round 4 isolates the VGPR-cap effect.
//
// k-order permutation trick: MFMA dot products are invariant under a shared
// permutation of the K dimension. q/k d-columns interleaved (col'=2*(d&15)
// +(d>>4)); vT m-columns permuted as pos = 8*((m>>2)&3)+4*((m>>4)&1)+(m&3)
// within each 32-block so the packed P fragment lines up with PV's A-operand.
// ---------------------------------------------------------------------------

typedef __attribute__((ext_vector_type(8))) short short8;   // 8 x bf16 frag
typedef __attribute__((ext_vector_type(4))) float f32x4;    // MFMA C/D
typedef unsigned short u16;
typedef unsigned int   u32;

#define SCALE_F 0.17677669529663687f  /* 32^-0.5 */

// LDS layout (attn): all byte offsets 16B-aligned
#define QS_OFF   0        // [216][40] u16 = 17280 (single: same-wave use)
#define KS0_OFF  17280    // [216][40] u16 = 17280
#define KS1_OFF  34560    // [216][40] u16 = 17280
#define VT0_OFF  51840    // [32][232] u16 = 14848 (perm cols; m-pads zeroed)
#define VT1_OFF  66688    // [32][232] u16 = 14848
#define ATTN_LDS 81536

#define PROJ_LDS 76800    // [192][200] u16 weights only -> 2 blocks/CU

__device__ __forceinline__ u16 f2bf(float f) {
  union { float f; u32 u; } v; v.f = f;
  return (u16)((v.u + 0x7fffu + ((v.u >> 16) & 1u)) >> 16);  // RNE
}

__device__ __forceinline__ f32x4 mfma16(short8 a, short8 b, f32x4 c) {
  return __builtin_amdgcn_mfma_f32_16x16x32_bf16(a, b, c, 0, 0, 0);
}

// ---------------------------------------------------------------------------
// K0: x->bf16 (upper half of each block's out region), qkv_w->bf16,
// proj_w->bf16, bias expand to [h][c][n:224][l:16][t:2] bf16.
// m = c*32 + t*16 + l. m>=216 -> -inf bf16 (0xFF80) so exp()->0. n>=216 -> 0.
// ---------------------------------------------------------------------------
__global__ void prep_kernel(const float* __restrict__ x,
                            const float* __restrict__ qkv_w,
                            const float* __restrict__ proj_w,
                            const float* __restrict__ bias_table,
                            u16* __restrict__ wb,
                            u16* __restrict__ pwb,
                            u16* __restrict__ biasp,
                            float* outbuf) {
  const int tid = blockIdx.x * blockDim.x + threadIdx.x;
  const int stride = gridDim.x * blockDim.x;
  // x -> bf16 scratch: block b's slice goes to bytes [82944, 165888) of its
  // own out region (lower part holds the [h][216][32] bf16 attn scratch).
  const float4* x4 = (const float4*)x;
  for (int i = tid; i < 1024 * 10368; i += stride) {
    const int b = i / 10368, r = i % 10368;
    const float4 v = x4[i];
    union { u16 s[4]; unsigned long long u; } pk;
    pk.s[0] = f2bf(v.x); pk.s[1] = f2bf(v.y);
    pk.s[2] = f2bf(v.z); pk.s[3] = f2bf(v.w);
    *(unsigned long long*)((u16*)(outbuf + (size_t)b * 41472) + 41472 + r * 4) = pk.u;
  }
  for (int i = tid; i < 576 * 192; i += stride) wb[i] = f2bf(qkv_w[i]);
  for (int i = tid; i < 192 * 192; i += stride) pwb[i] = f2bf(proj_w[i]);
  // bias layout: [h][c][n:224][l:16][t:2]; lane uint4 covers l=quad*4..+3.
  for (int i = tid; i < 6 * 7 * 224 * 16 * 2; i += stride) {
    const int t = i & 1;
    int j = i >> 1;
    const int l = j & 15;  j >>= 4;
    const int n = j % 224; j /= 224;
    const int c = j % 7;
    const int h = j / 7;
    const int m = c * 32 + t * 16 + l;
    u16 val;
    if (n >= 216)      val = 0;        // pad q-rows: finite, discarded
    else if (m >= 216) val = 0xFF80;   // -inf bf16 -> exp = 0
    else {
      const int di = n / 36 - m / 36;
      const int dj = (n / 6) % 6 - (m / 6) % 6;
      const int dk = n % 6 - m % 6;
      const int idx = (di + 5) * 17 + (dj + 5) * 11 + (dk + 5);
      val = f2bf(bias_table[idx * 6 + h]);
    }
    biasp[i] = val;
  }
}

// ---------------------------------------------------------------------------
// Fused step: phase2(h) from ksc/vtc/qs, interleaved with phase1(h+1) into
// ksn/vtn/qs (DOP1). qs hazard is same-wave only: qa read precedes qs writes
// in program order; compiler enforces LDS ordering via lgkmcnt.
// ---------------------------------------------------------------------------
template <bool DOP1>
__device__ __forceinline__ void head_step(
    int h, const u16* __restrict__ xb, const u16* __restrict__ wb,
    const u16* __restrict__ biasp, u16* __restrict__ attnb,
    u16* qs, const u16* ksc, const u16* vtc, u16* ksn, u16* vtn,
    int wave, int quad, int lcol) {
  const int s = wave;
  const int qr0 = s * 16 + lcol;
  const int qr  = qr0 < 216 ? qr0 : 215;      // clamp: garbage lanes discarded
  const short8 qa = *(const short8*)(qs + qr * 40 + quad * 8);

  f32x4 acc[6] = {};                          // phase1(h+1) accumulators
  const int ar = qr;                          // same clamped row for x

  f32x4 o0 = {}, o1 = {};
  float rsum = 0.0f;

#pragma unroll
  for (int c = 0; c < 7; ++c) {
    // ---- phase2 step c ----
    const short8 kb0 = *(const short8*)(ksc + (c * 32 + lcol) * 40 + quad * 8);
    const int kr1 = c * 32 + 16 + lcol;
    const short8 kb1 = *(const short8*)(ksc + (kr1 < 216 ? kr1 : 215) * 40 + quad * 8);
    const f32x4 z = {};
    const f32x4 s0 = mfma16(kb0, qa, z);      // S^T rows m=c*32+quad*4+r
    const f32x4 s1 = mfma16(kb1, qa, z);      // S^T rows m=c*32+16+quad*4+r
    const uint4 bq = *(const uint4*)(biasp
        + ((size_t)((h * 7 + c) * 224 + s * 16 + lcol)) * 32 + quad * 8);
    const u32* bw = (const u32*)&bq;
    float p0[4], p1[4];
#pragma unroll
    for (int r = 0; r < 4; ++r) {
      union { u32 u; float f; } b0, b1;
      b0.u = bw[r] << 16;            // t=0 bias (low short)
      b1.u = bw[r] & 0xFFFF0000u;    // t=1 bias (high short)
      p0[r] = __expf(__builtin_fmaf(s0[r], SCALE_F, b0.f));
      p1[r] = __expf(__builtin_fmaf(s1[r], SCALE_F, b1.f));
      rsum += p0[r] + p1[r];
    }
    union { u32 w[4]; short8 v; } pk;
    pk.w[0] = (u32)f2bf(p0[0]) | ((u32)f2bf(p0[1]) << 16);
    pk.w[1] = (u32)f2bf(p0[2]) | ((u32)f2bf(p0[3]) << 16);
    pk.w[2] = (u32)f2bf(p1[0]) | ((u32)f2bf(p1[1]) << 16);
    pk.w[3] = (u32)f2bf(p1[2]) | ((u32)f2bf(p1[3]) << 16);
    const short8 vb0 = *(const short8*)(vtc + lcol * 232 + c * 32 + quad * 8);
    const short8 vb1 = *(const short8*)(vtc + (16 + lcol) * 232 + c * 32 + quad * 8);
    o0 = mfma16(pk.v, vb0, o0);
    o1 = mfma16(pk.v, vb1, o1);

    // ---- phase1(h+1) step kk=c: independent MFMA stream fills the stalls ----
    if (DOP1 && c < 6) {
      const short8 a = *(const short8*)(xb + ar * 192 + c * 32 + quad * 8);
#pragma unroll
      for (int j = 0; j < 6; ++j) {    // 0,1=q(lo,hi) 2,3=k 4,5=v
        const int fbase = (j >> 1) * 192 + (h + 1) * 32 + (j & 1) * 16;
        const short8 bf = *(const short8*)(wb + (fbase + lcol) * 192 + c * 32 + quad * 8);
        acc[j] = mfma16(a, bf, acc[j]);
      }
    }
  }

  // ---- phase2 epilogue: denom + dense [h][216][32] store ----
  rsum += __shfl_xor(rsum, 16);
  rsum += __shfl_xor(rsum, 32);
  const float inv = 1.0f / rsum;
#pragma unroll
  for (int r = 0; r < 4; ++r) {
    const float invr = __shfl(inv, quad * 4 + r, 16);
    const int n = s * 16 + quad * 4 + r;
    if (n < 216) {
      attnb[(h * 216 + n) * 32 + lcol]      = f2bf(o0[r] * invr);
      attnb[(h * 216 + n) * 32 + 16 + lcol] = f2bf(o1[r] * invr);
    }
  }

  // ---- phase1(h+1) stores ----
  if (DOP1) {
    const int nb = s * 16 + quad * 4;
#pragma unroll
    for (int r = 0; r < 4; ++r) {
      const int n = nb + r;
      if (n < 216) {
        *(u32*)(qs + n * 40 + 2 * lcol) =
            (u32)f2bf(acc[0][r]) | ((u32)f2bf(acc[1][r]) << 16);
        *(u32*)(ksn + n * 40 + 2 * lcol) =
            (u32)f2bf(acc[2][r]) | ((u32)f2bf(acc[3][r]) << 16);
        const int pm = (n & ~31) | (((n >> 2) & 3) << 3) | (((n >> 4) & 1) << 2) | (n & 3);
        vtn[lcol * 232 + pm]        = f2bf(acc[4][r]);
        vtn[(16 + lcol) * 232 + pm] = f2bf(acc[5][r]);
      }
    }
  }
}

// ---------------------------------------------------------------------------
// K1: per-window fused qkv + attention, pipelined. 1024 thr, 1 block/CU,
// VGPR cap 128 (launch_bounds(1024,4)) -- the round-4 spill fix.
// ---------------------------------------------------------------------------
__global__ __launch_bounds__(1024, 4)
void attn_kernel(const u16* __restrict__ wb, const u16* __restrict__ biasp,
                 float* outbuf) {
  extern __shared__ char smem[];
  u16* qs  = (u16*)(smem + QS_OFF);
  u16* ks0 = (u16*)(smem + KS0_OFF);
  u16* ks1 = (u16*)(smem + KS1_OFF);
  u16* vt0 = (u16*)(smem + VT0_OFF);
  u16* vt1 = (u16*)(smem + VT1_OFF);

  const int b = blockIdx.x;
  const int tid = threadIdx.x;
  const int wave = tid >> 6;       // 0..13 active; 14,15 barrier-only
  const int lane = tid & 63;
  const int quad = lane >> 4;
  const int lcol = lane & 15;
  const bool active = wave < 14;

  const u16* xb    = (const u16*)(outbuf + (size_t)b * 41472) + 41472;  // [216][192]
  u16*       attnb = (u16*)(outbuf + (size_t)b * 41472);                // [6][216][32]

  // zero vT pad cols (perm positions 192+{20..23,28..31}) in BOTH buffers
  for (int i = tid; i < 512; i += 1024) {
    const int bufi = i >> 8;
    const int d  = (i >> 3) & 31;
    const int jj = i & 7;
    u16* vt = bufi ? vt1 : vt0;
    vt[d * 232 + 192 + 20 + (jj & 3) + ((jj >> 2) << 3)] = 0;
  }

  // ---- prologue: phase1(h=0) into qs/ks0/vt0 ----
  if (active) {
    f32x4 acc[6] = {};
    const int ar0 = wave * 16 + lcol;
    const int ar  = ar0 < 216 ? ar0 : 215;
#pragma unroll
    for (int kk = 0; kk < 6; ++kk) {
      const short8 a = *(const short8*)(xb + ar * 192 + kk * 32 + quad * 8);
#pragma unroll
      for (int j = 0; j < 6; ++j) {
        const int fbase = (j >> 1) * 192 + (j & 1) * 16;   // h=0
        const short8 bf = *(const short8*)(wb + (fbase + lcol) * 192 + kk * 32 + quad * 8);
        acc[j] = mfma16(a, bf, acc[j]);
      }
    }
    const int nb = wave * 16 + quad * 4;
#pragma unroll
    for (int r = 0; r < 4; ++r) {
      const int n = nb + r;
      if (n < 216) {
        *(u32*)(qs + n * 40 + 2 * lcol) =
            (u32)f2bf(acc[0][r]) | ((u32)f2bf(acc[1][r]) << 16);
        *(u32*)(ks0 + n * 40 + 2 * lcol) =
            (u32)f2bf(acc[2][r]) | ((u32)f2bf(acc[3][r]) << 16);
        const int pm = (n & ~31) | (((n >> 2) & 3) << 3) | (((n >> 4) & 1) << 2) | (n & 3);
        vt0[lcol * 232 + pm]        = f2bf(acc[4][r]);
        vt0[(16 + lcol) * 232 + pm] = f2bf(acc[5][r]);
      }
    }
  }
  __syncthreads();

  // ---- pipelined heads 0..4: phase2(h) || phase1(h+1) ----
  for (int h = 0; h < 5; ++h) {
    const bool even = (h & 1) == 0;
    const u16* ksc = even ? ks0 : ks1;
    const u16* vtc = even ? vt0 : vt1;
    u16* ksn = even ? ks1 : ks0;
    u16* vtn = even ? vt1 : vt0;
    if (active)
      head_step<true>(h, xb, wb, biasp, attnb, qs, ksc, vtc, ksn, vtn,
                      wave, quad, lcol);
    __syncthreads();
  }
  // ---- tail: phase2(5) only (buffers: h=5 -> odd -> ks1/vt1) ----
  if (active)
    head_step<false>(5, xb, wb, biasp, attnb, qs, ks1, vt1, ks0, vt0,
                     wave, quad, lcol);
}

// ---------------------------------------------------------------------------
// K2: out = attn @ proj_w^T + proj_b, block-local in-place on d_out.
// proj_w staged in LDS (padded stride 200); A-fragments loaded from GLOBAL
// attnb ([kk][216][32] bf16, dense) before the barrier; in-place fp32 writes
// after (the pre-barrier vmcnt drain orders all reads before any write).
// ---------------------------------------------------------------------------
__global__ __launch_bounds__(1024, 8)
void proj_kernel(const u16* __restrict__ pwb, const float* __restrict__ proj_b,
                 float* outbuf) {
  extern __shared__ char smem[];
  u16* pws = (u16*)smem;   // [192][200]
  const int b = blockIdx.x, tid = threadIdx.x;
  const int wave = tid >> 6, lane = tid & 63, quad = lane >> 4, lcol = lane & 15;
  float* myout = outbuf + (size_t)b * 41472;
  const u16* attnb = (const u16*)myout;   // [6][216][32]

  for (int i = tid; i < 192 * 24; i += 1024) {
    const int row = i / 24, c8 = i % 24;
    *(short8*)(pws + row * 200 + c8 * 8) = *(const short8*)(pwb + row * 192 + c8 * 8);
  }

  short8 a[6] = {};
  const bool active = wave < 14;
  if (active) {
    const int arow = wave * 16 + lcol;
    if (arow < 216) {
#pragma unroll
      for (int kk = 0; kk < 6; ++kk)
        a[kk] = *(const short8*)(attnb + (kk * 216 + arow) * 32 + quad * 8);
    }
  }
  __syncthreads();

  if (active) {
    for (int nt = 0; nt < 12; ++nt) {
      f32x4 acc = {};
#pragma unroll
      for (int kk = 0; kk < 6; ++kk) {
        const short8 bf = *(const short8*)(pws + (nt * 16 + lcol) * 200 + kk * 32 + quad * 8);
        acc = mfma16(a[kk], bf, acc);
      }
      const float pbv = proj_b[nt * 16 + lcol];
      const int nb = wave * 16 + quad * 4;
#pragma unroll
      for (int r = 0; r < 4; ++r) {
        const int n = nb + r;
        if (n < 216) myout[n * 192 + nt * 16 + lcol] = acc[r] + pbv;
      }
    }
  }
}

// ---------------------------------------------------------------------------
extern "C" void kernel_launch(void* const* d_in, const int* in_sizes, int n_in,
                              void* d_out, int out_size, void* d_ws, size_t ws_size,
                              hipStream_t stream) {
  (void)in_sizes; (void)n_in; (void)out_size; (void)ws_size;
  const float* x          = (const float*)d_in[0];
  const float* qkv_w      = (const float*)d_in[1];
  const float* proj_w     = (const float*)d_in[2];
  const float* proj_b     = (const float*)d_in[3];
  const float* bias_table = (const float*)d_in[4];
  float* out = (float*)d_out;

  u16* wb    = (u16*)d_ws;                              // 221184 B
  u16* pwb   = (u16*)((char*)d_ws + 221184);            //  73728 B
  u16* biasp = (u16*)((char*)d_ws + 294912);            // 602112 B

  (void)hipFuncSetAttribute((const void*)attn_kernel,
                            hipFuncAttributeMaxDynamicSharedMemorySize, ATTN_LDS);
  (void)hipFuncSetAttribute((const void*)proj_kernel,
                            hipFuncAttributeMaxDynamicSharedMemorySize, PROJ_LDS);

  prep_kernel<<<dim3(1024), dim3(256), 0, stream>>>(x, qkv_w, proj_w, bias_table,
                                                    wb, pwb, biasp, out);
  attn_kernel<<<dim3(1024), dim3(1024), ATTN_LDS, stream>>>(wb, biasp, out);
  proj_kernel<<<dim3(1024), dim3(1024), PROJ_LDS, stream>>>(pwb, proj_b, out);
}